// Round 2
// baseline (144.765 us; speedup 1.0000x reference)
//
#include <hip/hip_runtime.h>

// Downsample-by-2 along T with depthwise K=8 FIR, reflect pad=3.
// x: (4,64,128,4096) f32 -> 32768 rows of 4096.  y: 32768 rows of 2048.
// y[t] = sum_k w[k] * xp[2t+k],  xp[p] = x[reflect(p-3)]  (reflect excludes edge)

#define TLEN 4096
#define OLEN 2048
#define PAD 3
#define NTHREADS 256
#define NROWS 32768

__global__ __launch_bounds__(NTHREADS) void fir_down2_kernel(
    const float* __restrict__ x, const float* __restrict__ w,
    float* __restrict__ y)
{
    __shared__ float s[TLEN + 2 * PAD];  // 4102 floats = 16.4 KB

    const int tid = threadIdx.x;
    const long row = blockIdx.x;
    const float* __restrict__ xr = x + row * (long)TLEN;
    float* __restrict__ yr = y + row * (long)OLEN;

    // FIR taps (uniform address -> scalar loads, L2-cached broadcast)
    const float k0 = w[0], k1 = w[1], k2 = w[2], k3 = w[3];
    const float k4 = w[4], k5 = w[5], k6 = w[6], k7 = w[7];

    // Stage row into LDS at offset PAD: coalesced float4 loads (1 KB/wave/instr)
    const float4* __restrict__ x4 = (const float4*)xr;
#pragma unroll
    for (int j = 0; j < 4; ++j) {
        const int idx = tid + j * NTHREADS;   // 0..1023 float4s
        const float4 v = x4[idx];
        const int p = PAD + idx * 4;
        s[p + 0] = v.x; s[p + 1] = v.y; s[p + 2] = v.z; s[p + 3] = v.w;
    }
    // Reflect pads: s[p] = x[3-p] (left), s[4099+t] = x[4094-t] (right)
    if (tid < PAD) {
        s[tid] = xr[PAD - tid];
        s[TLEN + PAD + tid] = xr[TLEN - 2 - tid];
    }
    __syncthreads();

    // Each thread: 8 interleaved outputs. LDS read start = s[2t] (even ->
    // aligned b64 reads; lane stride 2 floats -> free 2-way bank aliasing).
#pragma unroll
    for (int it = 0; it < OLEN / NTHREADS; ++it) {
        const int t = tid + it * NTHREADS;
        const float* sp = s + 2 * t;
        const float acc = sp[0] * k0 + sp[1] * k1 + sp[2] * k2 + sp[3] * k3
                        + sp[4] * k4 + sp[5] * k5 + sp[6] * k6 + sp[7] * k7;
        yr[t] = acc;
    }
}

extern "C" void kernel_launch(void* const* d_in, const int* in_sizes, int n_in,
                              void* d_out, int out_size, void* d_ws, size_t ws_size,
                              hipStream_t stream) {
    const float* x = (const float*)d_in[0];
    const float* w = (const float*)d_in[1];
    float* y = (float*)d_out;
    fir_down2_kernel<<<NROWS, NTHREADS, 0, stream>>>(x, w, y);
}